// Round 2
// baseline (146.456 us; speedup 1.0000x reference)
//
#include <hip/hip_runtime.h>

// x: (8, 16, 3, 256, 256) f32.  out: (128, 2, 256, 256) f32.
// out[b*16+l, ch, hw] = (l>0) ? x[b,l,0,hw] - x[b,l-1,0,hw] : 0   (ch = 0,1)
//
// Temporal-loop version: each thread owns one float4 column (hw4) for 8
// consecutive l's, keeping the previous plane in registers -> every input
// plane is read from HBM exactly once (plus one boundary plane per b).
// Reads: 8 b * 17 planes * 256 KiB = 34 MiB. Writes: 64 MiB. ~15.6 us floor.

__global__ __launch_bounds__(256) void dummyflow_diff_kernel(
    const float4* __restrict__ x, float4* __restrict__ out) {
    constexpr int HW4 = 65536 / 4;                    // 16384 float4 per plane
    int idx  = blockIdx.x * blockDim.x + threadIdx.x; // [0, 16 * 16384)
    int hw4  = idx & (HW4 - 1);
    int seg  = idx >> 14;                             // 0..15 = b*2 + half
    int b    = seg >> 1;
    int half = seg & 1;
    int l0   = half * 8;

    const size_t inbase = (size_t)(b * 16) * 3 * HW4 + hw4;  // plane stride 3*HW4
    const size_t obase  = (size_t)(b * 16) * 2 * HW4 + hw4;  // plane stride 2*HW4

    float4 prv = make_float4(0.f, 0.f, 0.f, 0.f);
    if (half == 1)
        prv = x[inbase + (size_t)(l0 - 1) * 3 * HW4];

#pragma unroll
    for (int i = 0; i < 8; ++i) {
        int l = l0 + i;
        float4 cur = x[inbase + (size_t)l * 3 * HW4];
        float4 d;
        if (l == 0)
            d = make_float4(0.f, 0.f, 0.f, 0.f);
        else
            d = make_float4(cur.x - prv.x, cur.y - prv.y,
                            cur.z - prv.z, cur.w - prv.w);
        size_t o = obase + (size_t)l * 2 * HW4;
        out[o]       = d;   // ch 0
        out[o + HW4] = d;   // ch 1
        prv = cur;
    }
}

extern "C" void kernel_launch(void* const* d_in, const int* in_sizes, int n_in,
                              void* d_out, int out_size, void* d_ws, size_t ws_size,
                              hipStream_t stream) {
    const float4* x = (const float4*)d_in[0];
    float4* out     = (float4*)d_out;

    constexpr int HW4 = 65536 / 4;
    const int total = 16 * HW4;        // 8 b * 2 halves * 16384 columns
    const int block = 256;
    const int grid  = total / block;   // 1024 blocks -> 16 waves/CU

    dummyflow_diff_kernel<<<grid, block, 0, stream>>>(x, out);
}